// Round 2
// baseline (599.974 us; speedup 1.0000x reference)
//
#include <hip/hip_runtime.h>

// OrographyLatent: out[b,p,m] = sum_k (orog[b, nbr[p,k]] - bias_low[nbr[p,k]]) * W[p,k,m] + bias_high[p,m]
// B=8, H=W=256 -> NPIX=65536, K=25, MAP_DIM=64. All fp32, nbr int32 (check: int64 in ref!
// jnp.asarray of int64 -> JAX default int32 unless x64 enabled; harness passes int32).
// HBM-bound: W (419 MB) + out (128 MB) dominate. Read W once (shared over B),
// float4 loads/stores, nontemporal on streaming tensors.

typedef float f32x4 __attribute__((ext_vector_type(4)));

constexpr int NPIX = 65536;
constexpr int KN   = 25;
constexpr int MD   = 64;
constexpr int NB   = 8;
constexpr int PPW  = 4;            // pixels per wave (lane>>4 selects pixel)
constexpr int WPB  = 4;            // waves per block
constexpr int PPB  = PPW * WPB;    // 16 pixels per block

__global__ __launch_bounds__(256, 4)
void orog_latent_kernel(const float* __restrict__ orog,      // [NB][NPIX]
                        const int*   __restrict__ nbr,       // [NPIX][KN]
                        const float* __restrict__ bias_low,  // [NPIX]
                        const float* __restrict__ bias_high, // [NPIX][MD]
                        const float* __restrict__ wmap,      // [NPIX][KN][MD]
                        float*       __restrict__ out)       // [NB][NPIX][MD]
{
    // y_lds[slot][b][k]; slot stride = 8*25 = 200 words, 200 % 32 == 8 ->
    // the 4 ps-groups of a wave land on distinct banks; 16 lanes per group
    // read the same address (broadcast). Conflict-free. 12.8 KB/block.
    __shared__ float y_lds[PPB][NB][KN];

    const int tid  = threadIdx.x;
    const int wave = tid >> 6;
    const int lane = tid & 63;
    const int ps   = lane >> 4;    // which of the wave's 4 pixels
    const int m4   = lane & 15;    // which float4 column group of MD=64

    const int pix0 = blockIdx.x * PPB + wave * PPW;

    // ---- Phase 1: gather y = orog[b, idx] - bias_low[idx] into LDS ----
    // 4 pixels * 25 k = 100 items; lanes 0..35 do 2, rest 1.
    for (int item = lane; item < PPW * KN; item += 64) {
        const int   lps  = item / KN;         // 0..3
        const int   k    = item - lps * KN;   // 0..24
        const int   p    = pix0 + lps;
        const int   idx  = nbr[p * KN + k];
        const float bl   = bias_low[idx];
        const int   slot = wave * PPW + lps;
        #pragma unroll
        for (int b = 0; b < NB; ++b) {
            y_lds[slot][b][k] = orog[b * NPIX + idx] - bl;
        }
    }
    __syncthreads();

    // ---- Phase 2: per-lane dense accumulate over all 25 k ----
    const int p    = pix0 + ps;
    const int slot = wave * PPW + ps;
    const float* wrow = wmap + (size_t)p * (KN * MD) + (m4 << 2);

    float acc[NB][4];
    #pragma unroll
    for (int b = 0; b < NB; ++b) {
        acc[b][0] = 0.f; acc[b][1] = 0.f; acc[b][2] = 0.f; acc[b][3] = 0.f;
    }

    #pragma unroll 5
    for (int k = 0; k < KN; ++k) {
        // 16 lanes per pixel cover one 256 B row of W[p][k][:] -> 4 contiguous
        // 256 B segments per wave instruction. Streamed once: nontemporal.
        const f32x4 w4 = __builtin_nontemporal_load(
            reinterpret_cast<const f32x4*>(wrow + k * MD));
        #pragma unroll
        for (int b = 0; b < NB; ++b) {
            const float y = y_lds[slot][b][k];
            acc[b][0] = fmaf(y, w4.x, acc[b][0]);
            acc[b][1] = fmaf(y, w4.y, acc[b][1]);
            acc[b][2] = fmaf(y, w4.z, acc[b][2]);
            acc[b][3] = fmaf(y, w4.w, acc[b][3]);
        }
    }

    // ---- Epilogue: + bias_high, coalesced float4 nontemporal stores ----
    const f32x4 bh = __builtin_nontemporal_load(
        reinterpret_cast<const f32x4*>(bias_high + p * MD + (m4 << 2)));
    #pragma unroll
    for (int b = 0; b < NB; ++b) {
        f32x4 o;
        o.x = acc[b][0] + bh.x;
        o.y = acc[b][1] + bh.y;
        o.z = acc[b][2] + bh.z;
        o.w = acc[b][3] + bh.w;
        f32x4* dst = reinterpret_cast<f32x4*>(
            out + ((size_t)b * NPIX + p) * MD + (m4 << 2));
        __builtin_nontemporal_store(o, dst);
    }
}

extern "C" void kernel_launch(void* const* d_in, const int* in_sizes, int n_in,
                              void* d_out, int out_size, void* d_ws, size_t ws_size,
                              hipStream_t stream) {
    const float* orog      = (const float*)d_in[0];
    const int*   nbr       = (const int*)  d_in[1];
    const float* bias_low  = (const float*)d_in[2];
    const float* bias_high = (const float*)d_in[3];
    const float* wmap      = (const float*)d_in[4];
    float*       out       = (float*)d_out;

    dim3 grid(NPIX / PPB);   // 4096 blocks * 256 threads
    orog_latent_kernel<<<grid, 256, 0, stream>>>(orog, nbr, bias_low, bias_high,
                                                 wmap, out);
}